// Round 1
// baseline (1026.387 us; speedup 1.0000x reference)
//
#include <hip/hip_runtime.h>

#define Dh 128
#define NN 50000
#define EE 800000
#define RR 8
#define BB 4
#define LL 2
#define RK 1152           // RR*Dh + Dh  (8 relation slots + self-loop slot)
#define BN_EPS 1e-3f

// ---------------------------------------------------------------------------
// Build concatenated weight matrix per layer:
//   rows [0,1024): W[r][d][f] = sum_b w_coe[l,r,b] * bases[l,b,d,f]
//   rows [1024,1152): self_loop[l][d][f]
// ---------------------------------------------------------------------------
__global__ __launch_bounds__(256) void build_wcat_kernel(
    const float* __restrict__ bases, const float* __restrict__ w_coe,
    const float* __restrict__ self_loop, float* __restrict__ wcat)
{
    int idx = blockIdx.x * 256 + threadIdx.x;      // [0, LL*RK*Dh)
    int l = idx / (RK * Dh);
    int rem = idx - l * (RK * Dh);
    int row = rem >> 7;          // /128
    int f   = rem & 127;
    float val;
    if (row < RR * Dh) {
        int r = row >> 7;
        int d = row & 127;
        float acc = 0.f;
        #pragma unroll
        for (int b = 0; b < BB; b++) {
            float c = w_coe[(l * RR + r) * BB + b];
            float w = bases[(((l * BB + b) * Dh) + d) * Dh + f];
            acc += c * w;
        }
        val = acc;
    } else {
        int d = row - RR * Dh;
        val = self_loop[(l * Dh + d) * Dh + f];
    }
    wcat[(size_t)l * RK * Dh + (size_t)row * Dh + f] = val;
}

// ---------------------------------------------------------------------------
// Generic tiled GEMM: out[M x 128] = X[M x K] @ W[K x 128], fp32.
// mode 0: out = .. + bias[f]
// mode 1: out = relu(gamma*(..-mean)*rsqrt(var+eps)+beta)
// BM=64 rows/block, full 128 cols, BK=32. 256 threads, 32 outputs/thread.
// ---------------------------------------------------------------------------
__global__ __launch_bounds__(256) void gemm_kernel(
    const float* __restrict__ X, int K, const float* __restrict__ W,
    float* __restrict__ out,
    const float* __restrict__ bias,
    const float* __restrict__ bn_gamma, const float* __restrict__ bn_beta,
    const float* __restrict__ bn_mean, const float* __restrict__ bn_var,
    int mode, int M)
{
    __shared__ float a_s[64][32];
    __shared__ float w_s[32][Dh];
    int t  = threadIdx.x;
    int tx = t & 31;          // cols tx*4 .. tx*4+3
    int ty = t >> 5;          // rows ty*8 .. ty*8+7
    int row0 = blockIdx.x * 64;

    float acc[8][4];
    #pragma unroll
    for (int i = 0; i < 8; i++)
        #pragma unroll
        for (int j = 0; j < 4; j++) acc[i][j] = 0.f;

    for (int kk = 0; kk < K; kk += 32) {
        // stage X tile: 64x32 = 512 float4, 2 per thread
        #pragma unroll
        for (int i = 0; i < 2; i++) {
            int lin = t + 256 * i;           // 0..511
            int r   = lin >> 3;              // 8 float4 per row
            int c4  = lin & 7;
            int gr  = row0 + r;
            float4 v = make_float4(0.f, 0.f, 0.f, 0.f);
            if (gr < M) v = *(const float4*)&X[(size_t)gr * K + kk + c4 * 4];
            *(float4*)&a_s[r][c4 * 4] = v;
        }
        // stage W tile: 32x128 = 1024 float4, 4 per thread
        #pragma unroll
        for (int i = 0; i < 4; i++) {
            int lin = t + 256 * i;           // 0..1023
            int r   = lin >> 5;              // 32 float4 per row
            int c4  = lin & 31;
            *(float4*)&w_s[r][c4 * 4] = *(const float4*)&W[(size_t)(kk + r) * Dh + c4 * 4];
        }
        __syncthreads();
        #pragma unroll
        for (int k = 0; k < 32; k++) {
            float4 wv = *(float4*)&w_s[k][tx * 4];
            #pragma unroll
            for (int i = 0; i < 8; i++) {
                float av = a_s[ty * 8 + i][k];
                acc[i][0] += av * wv.x;
                acc[i][1] += av * wv.y;
                acc[i][2] += av * wv.z;
                acc[i][3] += av * wv.w;
            }
        }
        __syncthreads();
    }

    int col = tx * 4;
    float sc[4], sh[4];
    if (mode == 1) {
        #pragma unroll
        for (int j = 0; j < 4; j++) {
            float g = bn_gamma[col + j];
            float s = g * rsqrtf(bn_var[col + j] + BN_EPS);
            sc[j] = s;
            sh[j] = bn_beta[col + j] - bn_mean[col + j] * s;
        }
    } else {
        #pragma unroll
        for (int j = 0; j < 4; j++) { sc[j] = 1.f; sh[j] = bias[col + j]; }
    }
    #pragma unroll
    for (int i = 0; i < 8; i++) {
        int gr = row0 + ty * 8 + i;
        if (gr < M) {
            float4 o;
            float v0 = acc[i][0] * sc[0] + sh[0];
            float v1 = acc[i][1] * sc[1] + sh[1];
            float v2 = acc[i][2] * sc[2] + sh[2];
            float v3 = acc[i][3] * sc[3] + sh[3];
            if (mode == 1) {
                v0 = fmaxf(v0, 0.f); v1 = fmaxf(v1, 0.f);
                v2 = fmaxf(v2, 0.f); v3 = fmaxf(v3, 0.f);
            }
            o.x = v0; o.y = v1; o.z = v2; o.w = v3;
            *(float4*)&out[(size_t)gr * Dh + col] = o;
        }
    }
}

// ---------------------------------------------------------------------------
// Per-(node,relation) in-degree histogram
// ---------------------------------------------------------------------------
__global__ __launch_bounds__(256) void count_kernel(
    const int* __restrict__ dst, const int* __restrict__ etype,
    int* __restrict__ counts)
{
    int e = blockIdx.x * 256 + threadIdx.x;
    if (e < EE) atomicAdd(&counts[dst[e] * RR + etype[e]], 1);
}

// ---------------------------------------------------------------------------
// Per-node: norm = 1/cnt of the LAST relation with nonzero in-count
// (ascending overwrite semantics of the reference), deg = total in-degree.
// ---------------------------------------------------------------------------
__global__ __launch_bounds__(256) void norm_deg_kernel(
    const int* __restrict__ counts, float* __restrict__ node_norm,
    int* __restrict__ deg)
{
    int n = blockIdx.x * 256 + threadIdx.x;
    if (n >= NN) return;
    int total = 0; float norm = 0.f;
    #pragma unroll
    for (int r = 0; r < RR; r++) {
        int c = counts[n * RR + r];
        total += c;
        if (c > 0) norm = 1.0f / (float)c;   // later r overwrites
    }
    node_norm[n] = norm;
    deg[n] = total;
}

// ---------------------------------------------------------------------------
// Exclusive prefix scan over deg[N] -> row_ptr[N+1], cursor copy.
// Single block of 1024 threads, chunked Hillis-Steele.
// ---------------------------------------------------------------------------
__global__ __launch_bounds__(1024) void scan_kernel(
    const int* __restrict__ deg, int* __restrict__ row_ptr,
    int* __restrict__ cursor)
{
    __shared__ int sdata[1024];
    __shared__ int running;
    int t = threadIdx.x;
    if (t == 0) running = 0;
    __syncthreads();
    for (int base = 0; base < NN; base += 1024) {
        int n = base + t;
        int d = (n < NN) ? deg[n] : 0;
        sdata[t] = d;
        __syncthreads();
        for (int off = 1; off < 1024; off <<= 1) {
            int v = (t >= off) ? sdata[t - off] : 0;
            __syncthreads();
            sdata[t] += v;
            __syncthreads();
        }
        int excl = sdata[t] - d;
        int base_run = running;
        if (n < NN) {
            row_ptr[n] = base_run + excl;
            cursor[n]  = base_run + excl;
        }
        int total = sdata[1023];
        __syncthreads();
        if (t == 0) running = base_run + total;
        __syncthreads();
    }
    if (t == 0) row_ptr[NN] = running;
}

// ---------------------------------------------------------------------------
// Fill CSR: packed edge = src | (etype<<16)   (N < 2^16, R < 2^3)
// ---------------------------------------------------------------------------
__global__ __launch_bounds__(256) void fill_kernel(
    const int* __restrict__ src, const int* __restrict__ dst,
    const int* __restrict__ etype, int* __restrict__ cursor,
    unsigned* __restrict__ packed)
{
    int e = blockIdx.x * 256 + threadIdx.x;
    if (e < EE) {
        int d = dst[e];
        int pos = atomicAdd(&cursor[d], 1);
        packed[pos] = (unsigned)src[e] | ((unsigned)etype[e] << 16);
    }
}

// ---------------------------------------------------------------------------
// Aggregation: one block (128 threads) per node. Thread d accumulates
// slot r of X[n] = [norm*sum_{e in r} h[src] (r=0..7) | h[n]]  (1152 wide)
// ---------------------------------------------------------------------------
__global__ __launch_bounds__(128) void agg_kernel(
    const float* __restrict__ h, const int* __restrict__ row_ptr,
    const unsigned* __restrict__ packed, const float* __restrict__ node_norm,
    float* __restrict__ A)
{
    int n = blockIdx.x;
    int d = threadIdx.x;
    int s = row_ptr[n];
    int e = row_ptr[n + 1];
    float acc[RR];
    #pragma unroll
    for (int r = 0; r < RR; r++) acc[r] = 0.f;
    for (int i = s; i < e; i++) {
        unsigned p = packed[i];
        int srcn = (int)(p & 0xffffu);
        int et   = (int)(p >> 16);
        float v = h[srcn * Dh + d];
        #pragma unroll
        for (int r = 0; r < RR; r++) acc[r] += (et == r) ? v : 0.f;
    }
    float norm = node_norm[n];
    size_t base = (size_t)n * RK;
    #pragma unroll
    for (int r = 0; r < RR; r++) A[base + r * Dh + d] = acc[r] * norm;
    A[base + RR * Dh + d] = h[n * Dh + d];
}

// ---------------------------------------------------------------------------
extern "C" void kernel_launch(void* const* d_in, const int* in_sizes, int n_in,
                              void* d_out, int out_size, void* d_ws, size_t ws_size,
                              hipStream_t stream)
{
    const float* node_feat = (const float*)d_in[0];
    const float* W_emb     = (const float*)d_in[1];
    const float* b_emb     = (const float*)d_in[2];
    const float* bases     = (const float*)d_in[3];
    const float* w_coe     = (const float*)d_in[4];
    const float* self_loop = (const float*)d_in[5];
    const float* bn_gamma  = (const float*)d_in[6];
    const float* bn_beta   = (const float*)d_in[7];
    const float* bn_mean   = (const float*)d_in[8];
    const float* bn_var    = (const float*)d_in[9];
    const int*   src       = (const int*)d_in[10];
    const int*   dst       = (const int*)d_in[11];
    const int*   etype     = (const int*)d_in[12];
    float* out = (float*)d_out;

    char* ws = (char*)d_ws;
    size_t off = 0;
    float* A = (float*)(ws + off);          off += (size_t)NN * RK * 4;       // 230.4 MB
    float* h = (float*)(ws + off);          off += (size_t)NN * Dh * 4;       // 25.6 MB
    float* wcat = (float*)(ws + off);       off += (size_t)LL * RK * Dh * 4;  // 1.18 MB
    float* node_norm = (float*)(ws + off);  off += (size_t)NN * 4;
    int* counts = (int*)(ws + off);         off += (size_t)NN * RR * 4;
    int* deg = (int*)(ws + off);            off += (size_t)NN * 4;
    int* row_ptr = (int*)(ws + off);        off += ((size_t)NN + 4) * 4;
    int* cursor = (int*)(ws + off);         off += (size_t)NN * 4;
    unsigned* packed = (unsigned*)(ws + off); off += (size_t)EE * 4;

    const int gemm_blocks = (NN + 63) / 64;          // 782
    const int edge_blocks = (EE + 255) / 256;        // 3125
    const int node_blocks = (NN + 255) / 256;        // 196

    // weights
    build_wcat_kernel<<<(LL * RK * Dh) / 256, 256, 0, stream>>>(bases, w_coe, self_loop, wcat);

    // embedding: h = node_feat @ W_emb + b_emb
    gemm_kernel<<<gemm_blocks, 256, 0, stream>>>(node_feat, Dh, W_emb, h,
                                                 b_emb, nullptr, nullptr, nullptr, nullptr,
                                                 0, NN);

    // graph structure: counts -> norm/deg -> row_ptr -> CSR fill
    hipMemsetAsync(counts, 0, (size_t)NN * RR * 4, stream);
    count_kernel<<<edge_blocks, 256, 0, stream>>>(dst, etype, counts);
    norm_deg_kernel<<<node_blocks, 256, 0, stream>>>(counts, node_norm, deg);
    scan_kernel<<<1, 1024, 0, stream>>>(deg, row_ptr, cursor);
    fill_kernel<<<edge_blocks, 256, 0, stream>>>(src, dst, etype, cursor, packed);

    for (int l = 0; l < LL; l++) {
        agg_kernel<<<NN, 128, 0, stream>>>(h, row_ptr, packed, node_norm, A);
        float* dst_buf = (l == LL - 1) ? out : h;
        gemm_kernel<<<gemm_blocks, 256, 0, stream>>>(A, RK, wcat + (size_t)l * RK * Dh, dst_buf,
                                                     nullptr,
                                                     bn_gamma + l * Dh, bn_beta + l * Dh,
                                                     bn_mean + l * Dh, bn_var + l * Dh,
                                                     1, NN);
    }
}

// Round 3
// 608.280 us; speedup vs baseline: 1.6874x; 1.6874x over previous
//
#include <hip/hip_runtime.h>

#define Dh 128
#define NN 50000
#define EE 800000
#define RR 8
#define BB 4
#define LL 2
#define RK 1152           // RR*Dh + Dh  (8 relation slots + self-loop slot)
#define BN_EPS 1e-3f

typedef __attribute__((ext_vector_type(8))) short bf16x8;
typedef __attribute__((ext_vector_type(4))) float f32x4;

__device__ inline unsigned short f2bf(float x) {
    unsigned u = __float_as_uint(x);
    unsigned r = (u + 0x7fffu + ((u >> 16) & 1u)) >> 16;
    return (unsigned short)r;
}

// ---------------------------------------------------------------------------
// Weight prep (all tiny, launched once per call):
//   wcatT[l][f][k] (bf16): k in [0,1024) -> sum_b w_coe[l,r,b]*bases[l,b,d,f]
//                          (r=k>>7, d=k&127); k in [1024,1152) -> self_loop
//   wembT[f][d]    (bf16): transpose of W_emb
//   nf_bf          (bf16): node_feat cast
// ---------------------------------------------------------------------------
__global__ __launch_bounds__(256) void build_wcat_kernel(
    const float* __restrict__ bases, const float* __restrict__ w_coe,
    const float* __restrict__ self_loop, unsigned short* __restrict__ wcatT)
{
    int idx = blockIdx.x * 256 + threadIdx.x;      // [0, LL*RK*Dh)
    int l = idx / (RK * Dh);
    int rem = idx - l * (RK * Dh);
    int k = rem >> 7;            // row of the logical [RK x 128] weight
    int f = rem & 127;
    float val;
    if (k < RR * Dh) {
        int r = k >> 7;
        int d = k & 127;
        float acc = 0.f;
        #pragma unroll
        for (int b = 0; b < BB; b++) {
            float c = w_coe[(l * RR + r) * BB + b];
            float w = bases[(((l * BB + b) * Dh) + d) * Dh + f];
            acc += c * w;
        }
        val = acc;
    } else {
        int d = k - RR * Dh;
        val = self_loop[(l * Dh + d) * Dh + f];
    }
    wcatT[((size_t)l * Dh + f) * RK + k] = f2bf(val);
}

__global__ __launch_bounds__(256) void build_wembT_kernel(
    const float* __restrict__ W_emb, unsigned short* __restrict__ wembT)
{
    int idx = blockIdx.x * 256 + threadIdx.x;      // [0, 128*128)
    int f = idx >> 7;
    int d = idx & 127;
    wembT[f * Dh + d] = f2bf(W_emb[d * Dh + f]);
}

__global__ __launch_bounds__(256) void convert_nf_kernel(
    const float* __restrict__ nf, unsigned short* __restrict__ nf_bf, int n8)
{
    int idx = blockIdx.x * 256 + threadIdx.x;      // one per 8 elements
    if (idx >= n8) return;                         // OOB guard (r2 bug: wrote past nf_bf into wcatT)
    size_t base = (size_t)idx * 8;
    float4 v0 = *(const float4*)&nf[base];
    float4 v1 = *(const float4*)&nf[base + 4];
    unsigned short o[8] = { f2bf(v0.x), f2bf(v0.y), f2bf(v0.z), f2bf(v0.w),
                            f2bf(v1.x), f2bf(v1.y), f2bf(v1.z), f2bf(v1.w) };
    *(uint4*)&nf_bf[base] = *(uint4*)o;
}

// ---------------------------------------------------------------------------
// bf16 MFMA GEMM: out[M x 128] = A[M x K](bf16) @ Wt[128 x K](bf16)^T, fp32 acc.
// mode 0: +bias[f]; mode 1: relu(BN(..)).
// 128x128 block tile, BK=32, 256 threads (4 waves, one 64x64 quadrant each).
// A-frag: A[m=lane&15][k=(lane>>4)*8+j]; B-frag: B[n=lane&15][k=...];
// C/D: col=lane&15, row=(lane>>4)*4+reg   [m89/m91-verified layouts]
// ---------------------------------------------------------------------------
__global__ __launch_bounds__(256) void mfma_gemm_kernel(
    const unsigned short* __restrict__ A, int K,
    const unsigned short* __restrict__ Wt,
    float* __restrict__ out,
    const float* __restrict__ bias,
    const float* __restrict__ bn_gamma, const float* __restrict__ bn_beta,
    const float* __restrict__ bn_mean, const float* __restrict__ bn_var,
    int mode, int M)
{
    __shared__ unsigned short a_s[128][40];   // +8 pad: 2-way max bank alias
    __shared__ unsigned short b_s[128][40];
    int t    = threadIdx.x;
    int wave = t >> 6;
    int lane = t & 63;
    int wr   = (wave >> 1) * 64;     // wave's row quadrant
    int wc   = (wave & 1) * 64;      // wave's col quadrant
    int row0 = blockIdx.x * 128;

    int n16  = lane & 15;
    int quad = lane >> 4;

    f32x4 acc[4][4];
    #pragma unroll
    for (int i = 0; i < 4; i++)
        #pragma unroll
        for (int j = 0; j < 4; j++)
            acc[i][j] = (f32x4){0.f, 0.f, 0.f, 0.f};

    int srow  = t >> 1;              // staging: 2 threads per row
    int shalf = t & 1;               // each stages 16 bf16 = 32 B

    for (int kk = 0; kk < K; kk += 32) {
        int gr = row0 + srow;
        uint4 av0 = make_uint4(0u, 0u, 0u, 0u), av1 = av0;
        if (gr < M) {
            const uint4* gp = (const uint4*)&A[(size_t)gr * K + kk + shalf * 16];
            av0 = gp[0]; av1 = gp[1];
        }
        const uint4* wp = (const uint4*)&Wt[(size_t)srow * K + kk + shalf * 16];
        uint4 bv0 = wp[0], bv1 = wp[1];
        *(uint4*)&a_s[srow][shalf * 16]     = av0;
        *(uint4*)&a_s[srow][shalf * 16 + 8] = av1;
        *(uint4*)&b_s[srow][shalf * 16]     = bv0;
        *(uint4*)&b_s[srow][shalf * 16 + 8] = bv1;
        __syncthreads();

        bf16x8 af[4], bf[4];
        #pragma unroll
        for (int i = 0; i < 4; i++)
            af[i] = *(const bf16x8*)&a_s[wr + i * 16 + n16][quad * 8];
        #pragma unroll
        for (int j = 0; j < 4; j++)
            bf[j] = *(const bf16x8*)&b_s[wc + j * 16 + n16][quad * 8];
        #pragma unroll
        for (int i = 0; i < 4; i++)
            #pragma unroll
            for (int j = 0; j < 4; j++)
                acc[i][j] = __builtin_amdgcn_mfma_f32_16x16x32_bf16(
                    af[i], bf[j], acc[i][j], 0, 0, 0);
        __syncthreads();
    }

    // epilogue: per-column scale/shift
    float sc[4], sh[4];
    #pragma unroll
    for (int j = 0; j < 4; j++) {
        int c = wc + j * 16 + n16;
        if (mode == 1) {
            float s = bn_gamma[c] * rsqrtf(bn_var[c] + BN_EPS);
            sc[j] = s;
            sh[j] = bn_beta[c] - bn_mean[c] * s;
        } else {
            sc[j] = 1.f;
            sh[j] = bias[c];
        }
    }
    #pragma unroll
    for (int i = 0; i < 4; i++) {
        #pragma unroll
        for (int v = 0; v < 4; v++) {
            int gr = row0 + wr + i * 16 + quad * 4 + v;
            if (gr < M) {
                #pragma unroll
                for (int j = 0; j < 4; j++) {
                    float x = acc[i][j][v] * sc[j] + sh[j];
                    if (mode == 1) x = fmaxf(x, 0.f);
                    out[(size_t)gr * Dh + wc + j * 16 + n16] = x;
                }
            }
        }
    }
}

// ---------------------------------------------------------------------------
// Per-(node,relation) in-degree histogram
// ---------------------------------------------------------------------------
__global__ __launch_bounds__(256) void count_kernel(
    const int* __restrict__ dst, const int* __restrict__ etype,
    int* __restrict__ counts)
{
    int e = blockIdx.x * 256 + threadIdx.x;
    if (e < EE) atomicAdd(&counts[dst[e] * RR + etype[e]], 1);
}

// ---------------------------------------------------------------------------
// Per-node: norm = 1/cnt of the LAST relation with nonzero in-count
// (ascending overwrite semantics of the reference), deg = total in-degree.
// ---------------------------------------------------------------------------
__global__ __launch_bounds__(256) void norm_deg_kernel(
    const int* __restrict__ counts, float* __restrict__ node_norm,
    int* __restrict__ deg)
{
    int n = blockIdx.x * 256 + threadIdx.x;
    if (n >= NN) return;
    int total = 0; float norm = 0.f;
    #pragma unroll
    for (int r = 0; r < RR; r++) {
        int c = counts[n * RR + r];
        total += c;
        if (c > 0) norm = 1.0f / (float)c;   // later r overwrites
    }
    node_norm[n] = norm;
    deg[n] = total;
}

// ---------------------------------------------------------------------------
// Exclusive scan deg[N] -> row_ptr[N+1] (+cursor). One block, blocked scan:
// thread t owns elements [t*C, (t+1)*C); 10-step Hillis-Steele on partials.
// ---------------------------------------------------------------------------
__global__ __launch_bounds__(1024) void scan_kernel(
    const int* __restrict__ deg, int* __restrict__ row_ptr,
    int* __restrict__ cursor)
{
    __shared__ int part[1024];
    const int C = (NN + 1023) / 1024;        // 49
    int t = threadIdx.x;
    int start = t * C;
    int sum = 0;
    for (int i = 0; i < C; i++) {
        int n = start + i;
        if (n < NN) sum += deg[n];
    }
    part[t] = sum;
    __syncthreads();
    for (int off = 1; off < 1024; off <<= 1) {
        int v = (t >= off) ? part[t - off] : 0;
        __syncthreads();
        part[t] += v;
        __syncthreads();
    }
    int excl = part[t] - sum;
    for (int i = 0; i < C; i++) {
        int n = start + i;
        if (n < NN) {
            row_ptr[n] = excl;
            cursor[n]  = excl;
            excl += deg[n];
        }
    }
    if (t == 1023) row_ptr[NN] = part[1023];
}

// ---------------------------------------------------------------------------
// Fill CSR: packed edge = src | (etype<<16)   (N < 2^16, R < 2^3)
// ---------------------------------------------------------------------------
__global__ __launch_bounds__(256) void fill_kernel(
    const int* __restrict__ src, const int* __restrict__ dst,
    const int* __restrict__ etype, int* __restrict__ cursor,
    unsigned* __restrict__ packed)
{
    int e = blockIdx.x * 256 + threadIdx.x;
    if (e < EE) {
        int d = dst[e];
        int pos = atomicAdd(&cursor[d], 1);
        packed[pos] = (unsigned)src[e] | ((unsigned)etype[e] << 16);
    }
}

// ---------------------------------------------------------------------------
// Aggregation: one block (128 threads) per node, output X row in bf16:
// X[n] = [ norm * sum_{e: etype=r} h[src]  (r=0..7)  |  h[n] ]   (1152 wide)
// ---------------------------------------------------------------------------
__global__ __launch_bounds__(128) void agg_kernel(
    const float* __restrict__ h, const int* __restrict__ row_ptr,
    const unsigned* __restrict__ packed, const float* __restrict__ node_norm,
    unsigned short* __restrict__ A)
{
    int n = blockIdx.x;
    int d = threadIdx.x;
    int s = row_ptr[n];
    int e = row_ptr[n + 1];
    float acc[RR];
    #pragma unroll
    for (int r = 0; r < RR; r++) acc[r] = 0.f;
    for (int i = s; i < e; i++) {
        unsigned p = packed[i];
        int srcn = (int)(p & 0xffffu);
        int et   = (int)(p >> 16);
        float v = h[srcn * Dh + d];
        #pragma unroll
        for (int r = 0; r < RR; r++) acc[r] += (et == r) ? v : 0.f;
    }
    float norm = node_norm[n];
    size_t base = (size_t)n * RK;
    #pragma unroll
    for (int r = 0; r < RR; r++) A[base + r * Dh + d] = f2bf(acc[r] * norm);
    A[base + RR * Dh + d] = f2bf(h[n * Dh + d]);
}

// ---------------------------------------------------------------------------
extern "C" void kernel_launch(void* const* d_in, const int* in_sizes, int n_in,
                              void* d_out, int out_size, void* d_ws, size_t ws_size,
                              hipStream_t stream)
{
    const float* node_feat = (const float*)d_in[0];
    const float* W_emb     = (const float*)d_in[1];
    const float* b_emb     = (const float*)d_in[2];
    const float* bases     = (const float*)d_in[3];
    const float* w_coe     = (const float*)d_in[4];
    const float* self_loop = (const float*)d_in[5];
    const float* bn_gamma  = (const float*)d_in[6];
    const float* bn_beta   = (const float*)d_in[7];
    const float* bn_mean   = (const float*)d_in[8];
    const float* bn_var    = (const float*)d_in[9];
    const int*   src       = (const int*)d_in[10];
    const int*   dst       = (const int*)d_in[11];
    const int*   etype     = (const int*)d_in[12];
    float* out = (float*)d_out;

    char* ws = (char*)d_ws;
    size_t off = 0;
    unsigned short* A = (unsigned short*)(ws + off);      off += (size_t)NN * RK * 2;        // 115.2 MB
    float* h = (float*)(ws + off);                        off += (size_t)NN * Dh * 4;        // 25.6 MB
    unsigned short* nf_bf = (unsigned short*)(ws + off);  off += (size_t)NN * Dh * 2;        // 12.8 MB
    unsigned short* wcatT = (unsigned short*)(ws + off);  off += (size_t)LL * Dh * RK * 2;   // 0.6 MB
    unsigned short* wembT = (unsigned short*)(ws + off);  off += (size_t)Dh * Dh * 2;
    float* node_norm = (float*)(ws + off);                off += (size_t)NN * 4;
    int* counts = (int*)(ws + off);                       off += (size_t)NN * RR * 4;
    int* deg = (int*)(ws + off);                          off += (size_t)NN * 4;
    int* row_ptr = (int*)(ws + off);                      off += ((size_t)NN + 4) * 4;
    int* cursor = (int*)(ws + off);                       off += (size_t)NN * 4;
    unsigned* packed = (unsigned*)(ws + off);             off += (size_t)EE * 4;

    const int gemm_blocks = (NN + 127) / 128;        // 391
    const int edge_blocks = (EE + 255) / 256;        // 3125
    const int node_blocks = (NN + 255) / 256;        // 196
    const int n8 = NN * Dh / 8;                      // 800000, exactly 3125*256

    // weight prep + input conversion
    build_wcat_kernel<<<(LL * RK * Dh) / 256, 256, 0, stream>>>(bases, w_coe, self_loop, wcatT);
    build_wembT_kernel<<<(Dh * Dh) / 256, 256, 0, stream>>>(W_emb, wembT);
    convert_nf_kernel<<<(n8 + 255) / 256, 256, 0, stream>>>(node_feat, nf_bf, n8);

    // graph structure: counts -> norm/deg -> row_ptr -> CSR fill
    hipMemsetAsync(counts, 0, (size_t)NN * RR * 4, stream);
    count_kernel<<<edge_blocks, 256, 0, stream>>>(dst, etype, counts);
    norm_deg_kernel<<<node_blocks, 256, 0, stream>>>(counts, node_norm, deg);
    scan_kernel<<<1, 1024, 0, stream>>>(deg, row_ptr, cursor);
    fill_kernel<<<edge_blocks, 256, 0, stream>>>(src, dst, etype, cursor, packed);

    // embedding: h = node_feat @ W_emb + b_emb   (bf16 MFMA, fp32 out)
    mfma_gemm_kernel<<<gemm_blocks, 256, 0, stream>>>(nf_bf, Dh, wembT, h,
                                                      b_emb, nullptr, nullptr, nullptr, nullptr,
                                                      0, NN);

    for (int l = 0; l < LL; l++) {
        agg_kernel<<<NN, 128, 0, stream>>>(h, row_ptr, packed, node_norm, A);
        float* dst_buf = (l == LL - 1) ? out : h;
        mfma_gemm_kernel<<<gemm_blocks, 256, 0, stream>>>(A, RK, wcatT + (size_t)l * Dh * RK, dst_buf,
                                                          nullptr,
                                                          bn_gamma + l * Dh, bn_beta + l * Dh,
                                                          bn_mean + l * Dh, bn_var + l * Dh,
                                                          1, NN);
    }
}

// Round 4
// 503.174 us; speedup vs baseline: 2.0398x; 1.2089x over previous
//
#include <hip/hip_runtime.h>

#define Dh 128
#define NN 50000
#define EE 800000
#define RR 8
#define BB 4
#define LL 2
#define RK 1152           // RR*Dh + Dh  (8 relation slots + self-loop slot)
#define BN_EPS 1e-3f
#define NBLK 196          // (NN+255)/256

typedef __attribute__((ext_vector_type(8))) short bf16x8;
typedef __attribute__((ext_vector_type(4))) float f32x4;

__device__ inline unsigned short f2bf(float x) {
    unsigned u = __float_as_uint(x);
    unsigned r = (u + 0x7fffu + ((u >> 16) & 1u)) >> 16;
    return (unsigned short)r;
}

// ---------------------------------------------------------------------------
// Weight prep (all tiny, launched once per call):
//   wcatT[l][f][k] (bf16): k in [0,1024) -> sum_b w_coe[l,r,b]*bases[l,b,d,f]
//                          (r=k>>7, d=k&127); k in [1024,1152) -> self_loop
//   wembT[f][d]    (bf16): transpose of W_emb
//   nf_bf          (bf16): node_feat cast
// ---------------------------------------------------------------------------
__global__ __launch_bounds__(256) void build_wcat_kernel(
    const float* __restrict__ bases, const float* __restrict__ w_coe,
    const float* __restrict__ self_loop, unsigned short* __restrict__ wcatT)
{
    int idx = blockIdx.x * 256 + threadIdx.x;      // [0, LL*RK*Dh)
    int l = idx / (RK * Dh);
    int rem = idx - l * (RK * Dh);
    int k = rem >> 7;            // row of the logical [RK x 128] weight
    int f = rem & 127;
    float val;
    if (k < RR * Dh) {
        int r = k >> 7;
        int d = k & 127;
        float acc = 0.f;
        #pragma unroll
        for (int b = 0; b < BB; b++) {
            float c = w_coe[(l * RR + r) * BB + b];
            float w = bases[(((l * BB + b) * Dh) + d) * Dh + f];
            acc += c * w;
        }
        val = acc;
    } else {
        int d = k - RR * Dh;
        val = self_loop[(l * Dh + d) * Dh + f];
    }
    wcatT[((size_t)l * Dh + f) * RK + k] = f2bf(val);
}

__global__ __launch_bounds__(256) void build_wembT_kernel(
    const float* __restrict__ W_emb, unsigned short* __restrict__ wembT)
{
    int idx = blockIdx.x * 256 + threadIdx.x;      // [0, 128*128)
    int f = idx >> 7;
    int d = idx & 127;
    wembT[f * Dh + d] = f2bf(W_emb[d * Dh + f]);
}

__global__ __launch_bounds__(256) void convert_nf_kernel(
    const float* __restrict__ nf, unsigned short* __restrict__ nf_bf, int n8)
{
    int idx = blockIdx.x * 256 + threadIdx.x;      // one per 8 elements
    if (idx >= n8) return;                         // OOB guard (r2 bug: wrote past nf_bf into wcatT)
    size_t base = (size_t)idx * 8;
    float4 v0 = *(const float4*)&nf[base];
    float4 v1 = *(const float4*)&nf[base + 4];
    unsigned short o[8] = { f2bf(v0.x), f2bf(v0.y), f2bf(v0.z), f2bf(v0.w),
                            f2bf(v1.x), f2bf(v1.y), f2bf(v1.z), f2bf(v1.w) };
    *(uint4*)&nf_bf[base] = *(uint4*)o;
}

// ---------------------------------------------------------------------------
// bf16 MFMA GEMM: out[M x 128] = A[M x K](bf16) @ Wt[128 x K](bf16)^T, fp32 acc.
// mode 0: +bias[f]; mode 1: relu(BN(..)).
// 128x128 block tile, BK=32, 256 threads (4 waves, one 64x64 quadrant each).
// ---------------------------------------------------------------------------
__global__ __launch_bounds__(256) void mfma_gemm_kernel(
    const unsigned short* __restrict__ A, int K,
    const unsigned short* __restrict__ Wt,
    float* __restrict__ out,
    const float* __restrict__ bias,
    const float* __restrict__ bn_gamma, const float* __restrict__ bn_beta,
    const float* __restrict__ bn_mean, const float* __restrict__ bn_var,
    int mode, int M)
{
    __shared__ unsigned short a_s[128][40];   // +8 pad: 2-way max bank alias
    __shared__ unsigned short b_s[128][40];
    int t    = threadIdx.x;
    int wave = t >> 6;
    int lane = t & 63;
    int wr   = (wave >> 1) * 64;     // wave's row quadrant
    int wc   = (wave & 1) * 64;      // wave's col quadrant
    int row0 = blockIdx.x * 128;

    int n16  = lane & 15;
    int quad = lane >> 4;

    f32x4 acc[4][4];
    #pragma unroll
    for (int i = 0; i < 4; i++)
        #pragma unroll
        for (int j = 0; j < 4; j++)
            acc[i][j] = (f32x4){0.f, 0.f, 0.f, 0.f};

    int srow  = t >> 1;              // staging: 2 threads per row
    int shalf = t & 1;               // each stages 16 bf16 = 32 B

    for (int kk = 0; kk < K; kk += 32) {
        int gr = row0 + srow;
        uint4 av0 = make_uint4(0u, 0u, 0u, 0u), av1 = av0;
        if (gr < M) {
            const uint4* gp = (const uint4*)&A[(size_t)gr * K + kk + shalf * 16];
            av0 = gp[0]; av1 = gp[1];
        }
        const uint4* wp = (const uint4*)&Wt[(size_t)srow * K + kk + shalf * 16];
        uint4 bv0 = wp[0], bv1 = wp[1];
        *(uint4*)&a_s[srow][shalf * 16]     = av0;
        *(uint4*)&a_s[srow][shalf * 16 + 8] = av1;
        *(uint4*)&b_s[srow][shalf * 16]     = bv0;
        *(uint4*)&b_s[srow][shalf * 16 + 8] = bv1;
        __syncthreads();

        bf16x8 af[4], bf[4];
        #pragma unroll
        for (int i = 0; i < 4; i++)
            af[i] = *(const bf16x8*)&a_s[wr + i * 16 + n16][quad * 8];
        #pragma unroll
        for (int j = 0; j < 4; j++)
            bf[j] = *(const bf16x8*)&b_s[wc + j * 16 + n16][quad * 8];
        #pragma unroll
        for (int i = 0; i < 4; i++)
            #pragma unroll
            for (int j = 0; j < 4; j++)
                acc[i][j] = __builtin_amdgcn_mfma_f32_16x16x32_bf16(
                    af[i], bf[j], acc[i][j], 0, 0, 0);
        __syncthreads();
    }

    // epilogue: per-column scale/shift
    float sc[4], sh[4];
    #pragma unroll
    for (int j = 0; j < 4; j++) {
        int c = wc + j * 16 + n16;
        if (mode == 1) {
            float s = bn_gamma[c] * rsqrtf(bn_var[c] + BN_EPS);
            sc[j] = s;
            sh[j] = bn_beta[c] - bn_mean[c] * s;
        } else {
            sc[j] = 1.f;
            sh[j] = bias[c];
        }
    }
    #pragma unroll
    for (int i = 0; i < 4; i++) {
        #pragma unroll
        for (int v = 0; v < 4; v++) {
            int gr = row0 + wr + i * 16 + quad * 4 + v;
            if (gr < M) {
                #pragma unroll
                for (int j = 0; j < 4; j++) {
                    float x = acc[i][j][v] * sc[j] + sh[j];
                    if (mode == 1) x = fmaxf(x, 0.f);
                    out[(size_t)gr * Dh + wc + j * 16 + n16] = x;
                }
            }
        }
    }
}

// ---------------------------------------------------------------------------
// Per-(node,relation) in-degree histogram
// ---------------------------------------------------------------------------
__global__ __launch_bounds__(256) void count_kernel(
    const int* __restrict__ dst, const int* __restrict__ etype,
    int* __restrict__ counts)
{
    int e = blockIdx.x * 256 + threadIdx.x;
    if (e < EE) atomicAdd(&counts[dst[e] * RR + etype[e]], 1);
}

// ---------------------------------------------------------------------------
// Per-node: norm = 1/cnt of the LAST relation with nonzero in-count
// (ascending overwrite semantics of the reference), deg = total in-degree.
// ---------------------------------------------------------------------------
__global__ __launch_bounds__(256) void norm_deg_kernel(
    const int* __restrict__ counts, float* __restrict__ node_norm,
    int* __restrict__ deg)
{
    int n = blockIdx.x * 256 + threadIdx.x;
    if (n >= NN) return;
    int total = 0; float norm = 0.f;
    #pragma unroll
    for (int r = 0; r < RR; r++) {
        int c = counts[n * RR + r];
        total += c;
        if (c > 0) norm = 1.0f / (float)c;   // later r overwrites
    }
    node_norm[n] = norm;
    deg[n] = total;
}

// ---------------------------------------------------------------------------
// Device-wide exclusive scan of deg[NN] -> row_ptr/cursor, 3 kernels.
// (r3 post-mortem: single-block scan was 127 us, latency-bound on 1 CU.)
// ---------------------------------------------------------------------------
__global__ __launch_bounds__(256) void scan1_kernel(
    const int* __restrict__ deg, int* __restrict__ row_ptr,
    int* __restrict__ bsum)
{
    __shared__ int s[256];
    int t = threadIdx.x;
    int n = blockIdx.x * 256 + t;
    int d = (n < NN) ? deg[n] : 0;
    s[t] = d;
    __syncthreads();
    #pragma unroll
    for (int off = 1; off < 256; off <<= 1) {
        int v = (t >= off) ? s[t - off] : 0;
        __syncthreads();
        s[t] += v;
        __syncthreads();
    }
    if (n < NN) row_ptr[n] = s[t] - d;        // block-local exclusive
    if (t == 255) bsum[blockIdx.x] = s[255];  // block total
}

__global__ __launch_bounds__(256) void scan2_kernel(
    const int* __restrict__ bsum, int* __restrict__ boffset)
{
    __shared__ int s[256];
    int t = threadIdx.x;
    int d = (t < NBLK) ? bsum[t] : 0;
    s[t] = d;
    __syncthreads();
    #pragma unroll
    for (int off = 1; off < 256; off <<= 1) {
        int v = (t >= off) ? s[t - off] : 0;
        __syncthreads();
        s[t] += v;
        __syncthreads();
    }
    if (t <= NBLK) boffset[t] = s[t] - d;     // boffset[NBLK] == grand total
}

__global__ __launch_bounds__(256) void scan3_kernel(
    int* __restrict__ row_ptr, int* __restrict__ cursor,
    const int* __restrict__ boffset)
{
    int t = threadIdx.x;
    int n = blockIdx.x * 256 + t;
    if (n < NN) {
        int v = row_ptr[n] + boffset[blockIdx.x];
        row_ptr[n] = v;
        cursor[n]  = v;
    }
    if (blockIdx.x == 0 && t == 0) row_ptr[NN] = boffset[NBLK];
}

// ---------------------------------------------------------------------------
// Fill CSR: packed edge = src | (etype<<16)   (N < 2^16, R < 2^3)
// ---------------------------------------------------------------------------
__global__ __launch_bounds__(256) void fill_kernel(
    const int* __restrict__ src, const int* __restrict__ dst,
    const int* __restrict__ etype, int* __restrict__ cursor,
    unsigned* __restrict__ packed)
{
    int e = blockIdx.x * 256 + threadIdx.x;
    if (e < EE) {
        int d = dst[e];
        int pos = atomicAdd(&cursor[d], 1);
        packed[pos] = (unsigned)src[e] | ((unsigned)etype[e] << 16);
    }
}

// ---------------------------------------------------------------------------
// Aggregation: one block (128 threads) per node, output X row in bf16:
// X[n] = [ norm * sum_{e: etype=r} h[src]  (r=0..7)  |  h[n] ]   (1152 wide)
// ---------------------------------------------------------------------------
__global__ __launch_bounds__(128) void agg_kernel(
    const float* __restrict__ h, const int* __restrict__ row_ptr,
    const unsigned* __restrict__ packed, const float* __restrict__ node_norm,
    unsigned short* __restrict__ A)
{
    int n = blockIdx.x;
    int d = threadIdx.x;
    int s = row_ptr[n];
    int e = row_ptr[n + 1];
    float acc[RR];
    #pragma unroll
    for (int r = 0; r < RR; r++) acc[r] = 0.f;
    for (int i = s; i < e; i++) {
        unsigned p = packed[i];
        int srcn = (int)(p & 0xffffu);
        int et   = (int)(p >> 16);
        float v = h[srcn * Dh + d];
        #pragma unroll
        for (int r = 0; r < RR; r++) acc[r] += (et == r) ? v : 0.f;
    }
    float norm = node_norm[n];
    size_t base = (size_t)n * RK;
    #pragma unroll
    for (int r = 0; r < RR; r++) A[base + r * Dh + d] = f2bf(acc[r] * norm);
    A[base + RR * Dh + d] = f2bf(h[n * Dh + d]);
}

// ---------------------------------------------------------------------------
extern "C" void kernel_launch(void* const* d_in, const int* in_sizes, int n_in,
                              void* d_out, int out_size, void* d_ws, size_t ws_size,
                              hipStream_t stream)
{
    const float* node_feat = (const float*)d_in[0];
    const float* W_emb     = (const float*)d_in[1];
    const float* b_emb     = (const float*)d_in[2];
    const float* bases     = (const float*)d_in[3];
    const float* w_coe     = (const float*)d_in[4];
    const float* self_loop = (const float*)d_in[5];
    const float* bn_gamma  = (const float*)d_in[6];
    const float* bn_beta   = (const float*)d_in[7];
    const float* bn_mean   = (const float*)d_in[8];
    const float* bn_var    = (const float*)d_in[9];
    const int*   src       = (const int*)d_in[10];
    const int*   dst       = (const int*)d_in[11];
    const int*   etype     = (const int*)d_in[12];
    float* out = (float*)d_out;

    char* ws = (char*)d_ws;
    size_t off = 0;
    unsigned short* A = (unsigned short*)(ws + off);      off += (size_t)NN * RK * 2;        // 115.2 MB
    float* h = (float*)(ws + off);                        off += (size_t)NN * Dh * 4;        // 25.6 MB
    unsigned short* nf_bf = (unsigned short*)(ws + off);  off += (size_t)NN * Dh * 2;        // 12.8 MB
    unsigned short* wcatT = (unsigned short*)(ws + off);  off += (size_t)LL * Dh * RK * 2;   // 0.6 MB
    unsigned short* wembT = (unsigned short*)(ws + off);  off += (size_t)Dh * Dh * 2;
    float* node_norm = (float*)(ws + off);                off += (size_t)NN * 4;
    int* counts = (int*)(ws + off);                       off += (size_t)NN * RR * 4;
    int* deg = (int*)(ws + off);                          off += (size_t)NN * 4;
    int* row_ptr = (int*)(ws + off);                      off += ((size_t)NN + 4) * 4;
    int* cursor = (int*)(ws + off);                       off += (size_t)NN * 4;
    int* bsum = (int*)(ws + off);                         off += 256 * 4;
    int* boffset = (int*)(ws + off);                      off += 257 * 4;
    unsigned* packed = (unsigned*)(ws + off);             off += (size_t)EE * 4;

    const int gemm_blocks = (NN + 127) / 128;        // 391
    const int edge_blocks = (EE + 255) / 256;        // 3125
    const int node_blocks = (NN + 255) / 256;        // 196
    const int n8 = NN * Dh / 8;                      // 800000, exactly 3125*256

    // weight prep + input conversion
    build_wcat_kernel<<<(LL * RK * Dh) / 256, 256, 0, stream>>>(bases, w_coe, self_loop, wcatT);
    build_wembT_kernel<<<(Dh * Dh) / 256, 256, 0, stream>>>(W_emb, wembT);
    convert_nf_kernel<<<(n8 + 255) / 256, 256, 0, stream>>>(node_feat, nf_bf, n8);

    // graph structure: counts -> norm/deg -> scan -> CSR fill
    hipMemsetAsync(counts, 0, (size_t)NN * RR * 4, stream);
    count_kernel<<<edge_blocks, 256, 0, stream>>>(dst, etype, counts);
    norm_deg_kernel<<<node_blocks, 256, 0, stream>>>(counts, node_norm, deg);
    scan1_kernel<<<node_blocks, 256, 0, stream>>>(deg, row_ptr, bsum);
    scan2_kernel<<<1, 256, 0, stream>>>(bsum, boffset);
    scan3_kernel<<<node_blocks, 256, 0, stream>>>(row_ptr, cursor, boffset);
    fill_kernel<<<edge_blocks, 256, 0, stream>>>(src, dst, etype, cursor, packed);

    // embedding: h = node_feat @ W_emb + b_emb   (bf16 MFMA, fp32 out)
    mfma_gemm_kernel<<<gemm_blocks, 256, 0, stream>>>(nf_bf, Dh, wembT, h,
                                                      b_emb, nullptr, nullptr, nullptr, nullptr,
                                                      0, NN);

    for (int l = 0; l < LL; l++) {
        agg_kernel<<<NN, 128, 0, stream>>>(h, row_ptr, packed, node_norm, A);
        float* dst_buf = (l == LL - 1) ? out : h;
        mfma_gemm_kernel<<<gemm_blocks, 256, 0, stream>>>(A, RK, wcatT + (size_t)l * Dh * RK, dst_buf,
                                                          nullptr,
                                                          bn_gamma + l * Dh, bn_beta + l * Dh,
                                                          bn_mean + l * Dh, bn_var + l * Dh,
                                                          1, NN);
    }
}

// Round 5
// 479.142 us; speedup vs baseline: 2.1421x; 1.0502x over previous
//
#include <hip/hip_runtime.h>

#define Dh 128
#define NN 50000
#define EE 800000
#define RR 8
#define BB 4
#define LL 2
#define RK 1152           // RR*Dh + Dh  (8 relation slots + self-loop slot)
#define BN_EPS 1e-3f
#define NR (NN * RR)      // 400000 per-(node,rel) segments
#define NBLK2 ((NR + 255) / 256)   // 1563

typedef __attribute__((ext_vector_type(8))) short bf16x8;
typedef __attribute__((ext_vector_type(4))) float f32x4;

__device__ inline unsigned short f2bf(float x) {
    unsigned u = __float_as_uint(x);
    unsigned r = (u + 0x7fffu + ((u >> 16) & 1u)) >> 16;
    return (unsigned short)r;
}

// ---------------------------------------------------------------------------
// Weight prep (tiny):
//   wcatT[l][f][k] (bf16): k in [0,1024) -> sum_b w_coe[l,r,b]*bases[l,b,d,f]
//                          (r=k>>7, d=k&127); k in [1024,1152) -> self_loop
//   wembT[f][d]    (bf16): transpose of W_emb;  nf_bf: node_feat cast
// ---------------------------------------------------------------------------
__global__ __launch_bounds__(256) void build_wcat_kernel(
    const float* __restrict__ bases, const float* __restrict__ w_coe,
    const float* __restrict__ self_loop, unsigned short* __restrict__ wcatT)
{
    int idx = blockIdx.x * 256 + threadIdx.x;      // [0, LL*RK*Dh)
    int l = idx / (RK * Dh);
    int rem = idx - l * (RK * Dh);
    int k = rem >> 7;
    int f = rem & 127;
    float val;
    if (k < RR * Dh) {
        int r = k >> 7;
        int d = k & 127;
        float acc = 0.f;
        #pragma unroll
        for (int b = 0; b < BB; b++) {
            float c = w_coe[(l * RR + r) * BB + b];
            float w = bases[(((l * BB + b) * Dh) + d) * Dh + f];
            acc += c * w;
        }
        val = acc;
    } else {
        int d = k - RR * Dh;
        val = self_loop[(l * Dh + d) * Dh + f];
    }
    wcatT[((size_t)l * Dh + f) * RK + k] = f2bf(val);
}

__global__ __launch_bounds__(256) void build_wembT_kernel(
    const float* __restrict__ W_emb, unsigned short* __restrict__ wembT)
{
    int idx = blockIdx.x * 256 + threadIdx.x;      // [0, 128*128)
    int f = idx >> 7;
    int d = idx & 127;
    wembT[f * Dh + d] = f2bf(W_emb[d * Dh + f]);
}

__global__ __launch_bounds__(256) void convert_nf_kernel(
    const float* __restrict__ nf, unsigned short* __restrict__ nf_bf, int n8)
{
    int idx = blockIdx.x * 256 + threadIdx.x;      // one per 8 elements
    if (idx >= n8) return;                         // OOB guard (r2 bug)
    size_t base = (size_t)idx * 8;
    float4 v0 = *(const float4*)&nf[base];
    float4 v1 = *(const float4*)&nf[base + 4];
    unsigned short o[8] = { f2bf(v0.x), f2bf(v0.y), f2bf(v0.z), f2bf(v0.w),
                            f2bf(v1.x), f2bf(v1.y), f2bf(v1.z), f2bf(v1.w) };
    *(uint4*)&nf_bf[base] = *(uint4*)o;
}

// ---------------------------------------------------------------------------
// bf16 MFMA GEMM: out[M x 128] = A[M x K](bf16) @ Wt[128 x K](bf16)^T.
// mode 0: +bias[f]; mode 1: relu(BN(..)).  out_bf16: write bf16 else fp32.
// 128x128 tile, BK=32, 256 threads (4 waves, one 64x64 quadrant each).
// ---------------------------------------------------------------------------
__global__ __launch_bounds__(256) void mfma_gemm_kernel(
    const unsigned short* __restrict__ A, int K,
    const unsigned short* __restrict__ Wt,
    void* __restrict__ outp,
    const float* __restrict__ bias,
    const float* __restrict__ bn_gamma, const float* __restrict__ bn_beta,
    const float* __restrict__ bn_mean, const float* __restrict__ bn_var,
    int mode, int out_bf16, int M)
{
    __shared__ unsigned short a_s[128][40];
    __shared__ unsigned short b_s[128][40];
    int t    = threadIdx.x;
    int wave = t >> 6;
    int lane = t & 63;
    int wr   = (wave >> 1) * 64;
    int wc   = (wave & 1) * 64;
    int row0 = blockIdx.x * 128;

    int n16  = lane & 15;
    int quad = lane >> 4;

    f32x4 acc[4][4];
    #pragma unroll
    for (int i = 0; i < 4; i++)
        #pragma unroll
        for (int j = 0; j < 4; j++)
            acc[i][j] = (f32x4){0.f, 0.f, 0.f, 0.f};

    int srow  = t >> 1;
    int shalf = t & 1;

    for (int kk = 0; kk < K; kk += 32) {
        int gr = row0 + srow;
        uint4 av0 = make_uint4(0u, 0u, 0u, 0u), av1 = av0;
        if (gr < M) {
            const uint4* gp = (const uint4*)&A[(size_t)gr * K + kk + shalf * 16];
            av0 = gp[0]; av1 = gp[1];
        }
        const uint4* wp = (const uint4*)&Wt[(size_t)srow * K + kk + shalf * 16];
        uint4 bv0 = wp[0], bv1 = wp[1];
        *(uint4*)&a_s[srow][shalf * 16]     = av0;
        *(uint4*)&a_s[srow][shalf * 16 + 8] = av1;
        *(uint4*)&b_s[srow][shalf * 16]     = bv0;
        *(uint4*)&b_s[srow][shalf * 16 + 8] = bv1;
        __syncthreads();

        bf16x8 af[4], bf[4];
        #pragma unroll
        for (int i = 0; i < 4; i++)
            af[i] = *(const bf16x8*)&a_s[wr + i * 16 + n16][quad * 8];
        #pragma unroll
        for (int j = 0; j < 4; j++)
            bf[j] = *(const bf16x8*)&b_s[wc + j * 16 + n16][quad * 8];
        #pragma unroll
        for (int i = 0; i < 4; i++)
            #pragma unroll
            for (int j = 0; j < 4; j++)
                acc[i][j] = __builtin_amdgcn_mfma_f32_16x16x32_bf16(
                    af[i], bf[j], acc[i][j], 0, 0, 0);
        __syncthreads();
    }

    float sc[4], sh[4];
    #pragma unroll
    for (int j = 0; j < 4; j++) {
        int c = wc + j * 16 + n16;
        if (mode == 1) {
            float s = bn_gamma[c] * rsqrtf(bn_var[c] + BN_EPS);
            sc[j] = s;
            sh[j] = bn_beta[c] - bn_mean[c] * s;
        } else {
            sc[j] = 1.f;
            sh[j] = bias[c];
        }
    }
    #pragma unroll
    for (int i = 0; i < 4; i++) {
        #pragma unroll
        for (int v = 0; v < 4; v++) {
            int gr = row0 + wr + i * 16 + quad * 4 + v;
            if (gr < M) {
                #pragma unroll
                for (int j = 0; j < 4; j++) {
                    float x = acc[i][j][v] * sc[j] + sh[j];
                    if (mode == 1) x = fmaxf(x, 0.f);
                    size_t idx = (size_t)gr * Dh + wc + j * 16 + n16;
                    if (out_bf16) ((unsigned short*)outp)[idx] = f2bf(x);
                    else          ((float*)outp)[idx] = x;
                }
            }
        }
    }
}

// ---------------------------------------------------------------------------
// Per-(node,relation) in-degree histogram (doubles as scan input)
// ---------------------------------------------------------------------------
__global__ __launch_bounds__(256) void count_kernel(
    const int* __restrict__ dst, const int* __restrict__ etype,
    int* __restrict__ counts)
{
    int e = blockIdx.x * 256 + threadIdx.x;
    if (e < EE) atomicAdd(&counts[dst[e] * RR + etype[e]], 1);
}

// norm = 1/cnt of the LAST relation with nonzero in-count (ascending overwrite)
__global__ __launch_bounds__(256) void norm_kernel(
    const int* __restrict__ counts, float* __restrict__ node_norm)
{
    int n = blockIdx.x * 256 + threadIdx.x;
    if (n >= NN) return;
    float norm = 0.f;
    #pragma unroll
    for (int r = 0; r < RR; r++) {
        int c = counts[n * RR + r];
        if (c > 0) norm = 1.0f / (float)c;
    }
    node_norm[n] = norm;
}

// ---------------------------------------------------------------------------
// Device-wide exclusive scan of counts[NR] -> rp2/cursor2, 3 kernels.
// ---------------------------------------------------------------------------
__global__ __launch_bounds__(256) void scan1_kernel(
    const int* __restrict__ counts, int* __restrict__ rp2,
    int* __restrict__ bsum)
{
    __shared__ int s[256];
    int t = threadIdx.x;
    int n = blockIdx.x * 256 + t;
    int d = (n < NR) ? counts[n] : 0;
    s[t] = d;
    __syncthreads();
    #pragma unroll
    for (int off = 1; off < 256; off <<= 1) {
        int v = (t >= off) ? s[t - off] : 0;
        __syncthreads();
        s[t] += v;
        __syncthreads();
    }
    if (n < NR) rp2[n] = s[t] - d;
    if (t == 255) bsum[blockIdx.x] = s[255];
}

// single block, chunked over NBLK2 block sums
__global__ __launch_bounds__(256) void scan2_kernel(
    const int* __restrict__ bsum, int* __restrict__ boffset)
{
    __shared__ int s[256];
    __shared__ int run;
    int t = threadIdx.x;
    if (t == 0) run = 0;
    __syncthreads();
    for (int base = 0; base < NBLK2; base += 256) {
        int i = base + t;
        int d = (i < NBLK2) ? bsum[i] : 0;
        s[t] = d;
        __syncthreads();
        #pragma unroll
        for (int off = 1; off < 256; off <<= 1) {
            int v = (t >= off) ? s[t - off] : 0;
            __syncthreads();
            s[t] += v;
            __syncthreads();
        }
        int r0 = run;
        if (i < NBLK2) boffset[i] = r0 + s[t] - d;
        __syncthreads();
        if (t == 0) run = r0 + s[255];
        __syncthreads();
    }
}

__global__ __launch_bounds__(256) void scan3_kernel(
    int* __restrict__ rp2, int* __restrict__ cursor2,
    const int* __restrict__ boffset)
{
    int t = threadIdx.x;
    int n = blockIdx.x * 256 + t;
    if (n < NR) {
        int v = rp2[n] + boffset[blockIdx.x];
        rp2[n] = v;
        cursor2[n] = v;
    }
    if (blockIdx.x == 0 && t == 0) rp2[NR] = EE;   // grand total is always E
}

// ---------------------------------------------------------------------------
// Fill per-(node,rel) CSR: packed edge = src node id
// ---------------------------------------------------------------------------
__global__ __launch_bounds__(256) void fill_kernel(
    const int* __restrict__ src, const int* __restrict__ dst,
    const int* __restrict__ etype, int* __restrict__ cursor2,
    int* __restrict__ packed)
{
    int e = blockIdx.x * 256 + threadIdx.x;
    if (e < EE) {
        int pos = atomicAdd(&cursor2[dst[e] * RR + etype[e]], 1);
        packed[pos] = src[e];
    }
}

// ---------------------------------------------------------------------------
// Aggregation: one wave per node (4 nodes / 256-thread block). h is bf16;
// each lane owns 2 columns via one uint (2xbf16). Per relation r the edge
// segment [rp2[n*8+r], rp2[n*8+r+1]) is a plain sum — no predication.
// X[n] = [ norm * sum_r  |  h[n] ]  written as uints (2xbf16).
// ---------------------------------------------------------------------------
__global__ __launch_bounds__(256) void agg_kernel(
    const unsigned* __restrict__ h32, const int* __restrict__ rp2,
    const int* __restrict__ packed, const float* __restrict__ node_norm,
    unsigned* __restrict__ A32)
{
    int wave = threadIdx.x >> 6;
    int lane = threadIdx.x & 63;
    int n = blockIdx.x * 4 + wave;
    if (n >= NN) return;
    float norm = node_norm[n];
    unsigned self = h32[n * 64 + lane];
    size_t base = (size_t)n * (RK / 2);
    #pragma unroll
    for (int r = 0; r < RR; r++) {
        int s = rp2[n * RR + r];
        int e = rp2[n * RR + r + 1];
        float a0 = 0.f, a1 = 0.f;
        for (int i = s; i < e; i++) {
            int srcn = packed[i];
            unsigned hv = h32[srcn * 64 + lane];
            a0 += __uint_as_float(hv << 16);
            a1 += __uint_as_float(hv & 0xffff0000u);
        }
        unsigned o0 = f2bf(a0 * norm);
        unsigned o1 = f2bf(a1 * norm);
        A32[base + r * 64 + lane] = o0 | (o1 << 16);
    }
    A32[base + RR * 64 + lane] = self;
}

// ---------------------------------------------------------------------------
extern "C" void kernel_launch(void* const* d_in, const int* in_sizes, int n_in,
                              void* d_out, int out_size, void* d_ws, size_t ws_size,
                              hipStream_t stream)
{
    const float* node_feat = (const float*)d_in[0];
    const float* W_emb     = (const float*)d_in[1];
    const float* b_emb     = (const float*)d_in[2];
    const float* bases     = (const float*)d_in[3];
    const float* w_coe     = (const float*)d_in[4];
    const float* self_loop = (const float*)d_in[5];
    const float* bn_gamma  = (const float*)d_in[6];
    const float* bn_beta   = (const float*)d_in[7];
    const float* bn_mean   = (const float*)d_in[8];
    const float* bn_var    = (const float*)d_in[9];
    const int*   src       = (const int*)d_in[10];
    const int*   dst       = (const int*)d_in[11];
    const int*   etype     = (const int*)d_in[12];

    char* ws = (char*)d_ws;
    size_t off = 0;
    unsigned short* A = (unsigned short*)(ws + off);      off += (size_t)NN * RK * 2;        // 115.2 MB
    unsigned short* h = (unsigned short*)(ws + off);      off += (size_t)NN * Dh * 2;        // 12.8 MB
    unsigned short* nf_bf = (unsigned short*)(ws + off);  off += (size_t)NN * Dh * 2;        // 12.8 MB
    unsigned short* wcatT = (unsigned short*)(ws + off);  off += (size_t)LL * Dh * RK * 2;   // 0.6 MB
    unsigned short* wembT = (unsigned short*)(ws + off);  off += (size_t)Dh * Dh * 2;
    float* node_norm = (float*)(ws + off);                off += (size_t)NN * 4;
    int* counts = (int*)(ws + off);                       off += (size_t)NR * 4;             // 1.6 MB
    int* rp2 = (int*)(ws + off);                          off += ((size_t)NR + 4) * 4;       // 1.6 MB
    int* cursor2 = (int*)(ws + off);                      off += (size_t)NR * 4;             // 1.6 MB
    int* bsum = (int*)(ws + off);                         off += (size_t)NBLK2 * 4;
    int* boffset = (int*)(ws + off);                      off += (size_t)NBLK2 * 4;
    int* packed = (int*)(ws + off);                       off += (size_t)EE * 4;             // 3.2 MB

    const int gemm_blocks = (NN + 127) / 128;        // 391
    const int edge_blocks = (EE + 255) / 256;        // 3125
    const int node_blocks = (NN + 255) / 256;        // 196
    const int n8 = NN * Dh / 8;                      // 800000

    // weight prep + input conversion
    build_wcat_kernel<<<(LL * RK * Dh) / 256, 256, 0, stream>>>(bases, w_coe, self_loop, wcatT);
    build_wembT_kernel<<<(Dh * Dh) / 256, 256, 0, stream>>>(W_emb, wembT);
    convert_nf_kernel<<<(n8 + 255) / 256, 256, 0, stream>>>(node_feat, nf_bf, n8);

    // graph structure: per-(node,rel) counts -> norm -> scan -> CSR fill
    hipMemsetAsync(counts, 0, (size_t)NR * 4, stream);
    count_kernel<<<edge_blocks, 256, 0, stream>>>(dst, etype, counts);
    norm_kernel<<<node_blocks, 256, 0, stream>>>(counts, node_norm);
    scan1_kernel<<<NBLK2, 256, 0, stream>>>(counts, rp2, bsum);
    scan2_kernel<<<1, 256, 0, stream>>>(bsum, boffset);
    scan3_kernel<<<NBLK2, 256, 0, stream>>>(rp2, cursor2, boffset);
    fill_kernel<<<edge_blocks, 256, 0, stream>>>(src, dst, etype, cursor2, packed);

    // embedding: h = bf16(node_feat @ W_emb + b_emb)
    mfma_gemm_kernel<<<gemm_blocks, 256, 0, stream>>>(nf_bf, Dh, wembT, h,
                                                      b_emb, nullptr, nullptr, nullptr, nullptr,
                                                      0, 1, NN);

    for (int l = 0; l < LL; l++) {
        agg_kernel<<<(NN + 3) / 4, 256, 0, stream>>>((const unsigned*)h, rp2, packed,
                                                     node_norm, (unsigned*)A);
        int last = (l == LL - 1);
        void* dst_buf = last ? d_out : (void*)h;
        mfma_gemm_kernel<<<gemm_blocks, 256, 0, stream>>>(A, RK, wcatT + (size_t)l * Dh * RK,
                                                          dst_buf, nullptr,
                                                          bn_gamma + l * Dh, bn_beta + l * Dh,
                                                          bn_mean + l * Dh, bn_var + l * Dh,
                                                          1, last ? 0 : 1, NN);
    }
}

// Round 7
// 468.670 us; speedup vs baseline: 2.1900x; 1.0223x over previous
//
#include <hip/hip_runtime.h>

#define Dh 128
#define NN 50000
#define EE 800000
#define RR 8
#define BB 4
#define LL 2
#define NW 1152           // 8 relation blocks + self block, wide-GEMM N
#define TROW 576          // NW/2 uints per T row
#define BN_EPS 1e-3f
#define NR (NN * RR)
#define NBLK 196          // (NN+255)/256

typedef __attribute__((ext_vector_type(8))) short bf16x8;
typedef __attribute__((ext_vector_type(4))) float f32x4;

__device__ inline unsigned short f2bf(float x) {
    unsigned u = __float_as_uint(x);
    unsigned r = (u + 0x7fffu + ((u >> 16) & 1u)) >> 16;
    return (unsigned short)r;
}

// ---------------------------------------------------------------------------
// wideT[l][f][c] (fp32) = Wwide_l^T : f in [0,1024): sum_b w_coe[l,r,b]*bases[l,b,c,f&127]
//                         f in [1024,1152): self_loop[l,c,f&127]
// Also emits bf16 wcatT1 (layer-1 GEMM B operand, [f][c]).
// ---------------------------------------------------------------------------
__global__ __launch_bounds__(256) void build_wideT_kernel(
    const float* __restrict__ bases, const float* __restrict__ w_coe,
    const float* __restrict__ self_loop, float* __restrict__ wideT,
    unsigned short* __restrict__ wcatT1)
{
    int idx = blockIdx.x * 256 + threadIdx.x;      // [0, LL*NW*128)
    int l = idx / (NW * Dh);
    int rem = idx - l * (NW * Dh);
    int f = rem >> 7;
    int c = rem & 127;
    float val;
    if (f < RR * Dh) {
        int r = f >> 7;
        float acc = 0.f;
        #pragma unroll
        for (int b = 0; b < BB; b++) {
            float co = w_coe[(l * RR + r) * BB + b];
            float w = bases[(((l * BB + b) * Dh) + c) * Dh + (f & 127)];
            acc += co * w;
        }
        val = acc;
    } else {
        val = self_loop[(l * Dh + c) * Dh + (f & 127)];
    }
    wideT[(size_t)l * NW * Dh + (size_t)f * Dh + c] = val;
    if (l == 1) wcatT1[(size_t)f * Dh + c] = f2bf(val);
}

// wembT32[c][d] = W_emb[d][c]  (fp32 transpose, for coalesced folding)
__global__ __launch_bounds__(256) void build_wembT_kernel(
    const float* __restrict__ W_emb, float* __restrict__ wembT32)
{
    int idx = blockIdx.x * 256 + threadIdx.x;      // [0, 128*128)
    int c = idx >> 7;
    int d = idx & 127;
    wembT32[c * Dh + d] = W_emb[d * Dh + c];
}

// WF0T[f][d] (bf16) = sum_c wideT0[f][c] * W_emb[d][c]   (embed folded into layer 0)
__global__ __launch_bounds__(256) void fold_w_kernel(
    const float* __restrict__ wideT0, const float* __restrict__ wembT32,
    unsigned short* __restrict__ WF0T)
{
    int idx = blockIdx.x * 256 + threadIdx.x;      // [0, NW*128)
    int f = idx >> 7;
    int d = idx & 127;
    float acc = 0.f;
    for (int c = 0; c < Dh; c++)
        acc += wideT0[f * Dh + c] * wembT32[c * Dh + d];
    WF0T[(size_t)f * Dh + d] = f2bf(acc);
}

// bf0[f] = sum_c wideT0[f][c] * b_emb[c]
__global__ __launch_bounds__(256) void fold_b_kernel(
    const float* __restrict__ wideT0, const float* __restrict__ b_emb,
    float* __restrict__ bf0)
{
    int f = blockIdx.x * 256 + threadIdx.x;
    if (f >= NW) return;
    float acc = 0.f;
    for (int c = 0; c < Dh; c++) acc += wideT0[f * Dh + c] * b_emb[c];
    bf0[f] = acc;
}

__global__ __launch_bounds__(256) void convert_nf_kernel(
    const float* __restrict__ nf, unsigned short* __restrict__ nf_bf, int n8)
{
    int idx = blockIdx.x * 256 + threadIdx.x;      // one per 8 elements
    if (idx >= n8) return;                         // OOB guard (r2 lesson)
    size_t base = (size_t)idx * 8;
    float4 v0 = *(const float4*)&nf[base];
    float4 v1 = *(const float4*)&nf[base + 4];
    unsigned short o[8] = { f2bf(v0.x), f2bf(v0.y), f2bf(v0.z), f2bf(v0.w),
                            f2bf(v1.x), f2bf(v1.y), f2bf(v1.z), f2bf(v1.w) };
    *(uint4*)&nf_bf[base] = *(uint4*)o;
}

// ---------------------------------------------------------------------------
// Wide MFMA GEMM: T[M x 1152](bf16) = A[M x 128](bf16) @ Wt[1152 x 128]^T (+bias).
// K=128 (single staged pass). Grid (391, 9); 128x128 out tile, 4 waves.
// Staging: 2 threads/row, each stages 8 uint4 = 64 bf16  (r6 bug: staged only 16).
// ---------------------------------------------------------------------------
__global__ __launch_bounds__(256) void gemm_wide_kernel(
    const unsigned short* __restrict__ A,
    const unsigned short* __restrict__ Wt,
    const float* __restrict__ bias,          // may be null
    unsigned short* __restrict__ T, int M)
{
    __shared__ unsigned short a_s[128][136];   // 136: +8 pad
    __shared__ unsigned short b_s[128][136];
    int t    = threadIdx.x;
    int wave = t >> 6;
    int lane = t & 63;
    int wr   = (wave >> 1) * 64;
    int wc   = (wave & 1) * 64;
    int row0 = blockIdx.x * 128;
    int col0 = blockIdx.y * 128;
    int n16  = lane & 15;
    int quad = lane >> 4;

    // stage full 128-wide K rows: thread t -> row t>>1, half t&1 (64 bf16 = 8 uint4)
    {
        int srow = t >> 1, shalf = t & 1;
        int gr = row0 + srow;
        const uint4* gp = (const uint4*)&A[(size_t)gr * Dh + shalf * 64];
        const uint4* wp = (const uint4*)&Wt[(size_t)(col0 + srow) * Dh + shalf * 64];
        #pragma unroll
        for (int i = 0; i < 8; i++) {
            uint4 av = make_uint4(0u, 0u, 0u, 0u);
            if (gr < M) av = gp[i];
            uint4 bv = wp[i];
            *(uint4*)&a_s[srow][shalf * 64 + i * 8] = av;
            *(uint4*)&b_s[srow][shalf * 64 + i * 8] = bv;
        }
    }
    __syncthreads();

    f32x4 acc[4][4];
    #pragma unroll
    for (int i = 0; i < 4; i++)
        #pragma unroll
        for (int j = 0; j < 4; j++)
            acc[i][j] = (f32x4){0.f, 0.f, 0.f, 0.f};

    #pragma unroll
    for (int kc = 0; kc < 4; kc++) {
        bf16x8 af[4], bf[4];
        #pragma unroll
        for (int i = 0; i < 4; i++)
            af[i] = *(const bf16x8*)&a_s[wr + i * 16 + n16][kc * 32 + quad * 8];
        #pragma unroll
        for (int j = 0; j < 4; j++)
            bf[j] = *(const bf16x8*)&b_s[wc + j * 16 + n16][kc * 32 + quad * 8];
        #pragma unroll
        for (int i = 0; i < 4; i++)
            #pragma unroll
            for (int j = 0; j < 4; j++)
                acc[i][j] = __builtin_amdgcn_mfma_f32_16x16x32_bf16(
                    af[i], bf[j], acc[i][j], 0, 0, 0);
    }

    float bj[4];
    #pragma unroll
    for (int j = 0; j < 4; j++)
        bj[j] = bias ? bias[col0 + wc + j * 16 + n16] : 0.f;

    #pragma unroll
    for (int i = 0; i < 4; i++) {
        #pragma unroll
        for (int v = 0; v < 4; v++) {
            int gr = row0 + wr + i * 16 + quad * 4 + v;
            if (gr < M) {
                #pragma unroll
                for (int j = 0; j < 4; j++)
                    T[(size_t)gr * NW + col0 + wc + j * 16 + n16] =
                        f2bf(acc[i][j][v] + bj[j]);
            }
        }
    }
}

// ---------------------------------------------------------------------------
// Per-(node,relation) histogram (for norm), then per-node norm + total degree
// ---------------------------------------------------------------------------
__global__ __launch_bounds__(256) void count_kernel(
    const int* __restrict__ dst, const int* __restrict__ etype,
    int* __restrict__ counts)
{
    int e = blockIdx.x * 256 + threadIdx.x;
    if (e < EE) atomicAdd(&counts[dst[e] * RR + etype[e]], 1);
}

__global__ __launch_bounds__(256) void norm_deg_kernel(
    const int* __restrict__ counts, float* __restrict__ node_norm,
    int* __restrict__ deg)
{
    int n = blockIdx.x * 256 + threadIdx.x;
    if (n >= NN) return;
    int total = 0; float norm = 0.f;
    #pragma unroll
    for (int r = 0; r < RR; r++) {
        int c = counts[n * RR + r];
        total += c;
        if (c > 0) norm = 1.0f / (float)c;   // later r overwrites (ref semantics)
    }
    node_norm[n] = norm;
    deg[n] = total;
}

// ---------------------------------------------------------------------------
// Device-wide exclusive scan of deg[NN] -> row_ptr/cursor (3 kernels)
// ---------------------------------------------------------------------------
__global__ __launch_bounds__(256) void scan1_kernel(
    const int* __restrict__ deg, int* __restrict__ row_ptr,
    int* __restrict__ bsum)
{
    __shared__ int s[256];
    int t = threadIdx.x;
    int n = blockIdx.x * 256 + t;
    int d = (n < NN) ? deg[n] : 0;
    s[t] = d;
    __syncthreads();
    #pragma unroll
    for (int off = 1; off < 256; off <<= 1) {
        int v = (t >= off) ? s[t - off] : 0;
        __syncthreads();
        s[t] += v;
        __syncthreads();
    }
    if (n < NN) row_ptr[n] = s[t] - d;
    if (t == 255) bsum[blockIdx.x] = s[255];
}

__global__ __launch_bounds__(256) void scan2_kernel(
    const int* __restrict__ bsum, int* __restrict__ boffset)
{
    __shared__ int s[256];
    int t = threadIdx.x;
    int d = (t < NBLK) ? bsum[t] : 0;
    s[t] = d;
    __syncthreads();
    #pragma unroll
    for (int off = 1; off < 256; off <<= 1) {
        int v = (t >= off) ? s[t - off] : 0;
        __syncthreads();
        s[t] += v;
        __syncthreads();
    }
    if (t <= NBLK) boffset[t] = s[t] - d;
}

__global__ __launch_bounds__(256) void scan3_kernel(
    int* __restrict__ row_ptr, int* __restrict__ cursor,
    const int* __restrict__ boffset)
{
    int t = threadIdx.x;
    int n = blockIdx.x * 256 + t;
    if (n < NN) {
        int v = row_ptr[n] + boffset[blockIdx.x];
        row_ptr[n] = v;
        cursor[n]  = v;
    }
    if (blockIdx.x == 0 && t == 0) row_ptr[NN] = EE;
}

// ---------------------------------------------------------------------------
// Fill per-node CSR: packed edge = src | (etype<<16)
// ---------------------------------------------------------------------------
__global__ __launch_bounds__(256) void fill_kernel(
    const int* __restrict__ src, const int* __restrict__ dst,
    const int* __restrict__ etype, int* __restrict__ cursor,
    unsigned* __restrict__ packed)
{
    int e = blockIdx.x * 256 + threadIdx.x;
    if (e < EE) {
        int pos = atomicAdd(&cursor[dst[e]], 1);
        packed[pos] = (unsigned)src[e] | ((unsigned)etype[e] << 16);
    }
}

// ---------------------------------------------------------------------------
// Fused aggregation + BN + ReLU. One wave per node; lane owns cols (2l,2l+1)
// of the 128-wide output. Relation sum collapses into ONE accumulator:
//   out[n] = BN( norm * sum_e T[src_e, et_e*128 ..] + T[n, self] ), ReLU
// Gather address = src*576 + et*64 + lane (uints of bf16 pairs).
// out_fp32: write d_out fp32 (float2), else h' bf16 (uint).
// ---------------------------------------------------------------------------
__global__ __launch_bounds__(256) void agg_fused_kernel(
    const unsigned* __restrict__ T32, const int* __restrict__ row_ptr,
    const unsigned* __restrict__ packed, const float* __restrict__ node_norm,
    const float* __restrict__ bn_gamma, const float* __restrict__ bn_beta,
    const float* __restrict__ bn_mean, const float* __restrict__ bn_var,
    void* __restrict__ outp, int out_fp32)
{
    int wave = threadIdx.x >> 6;
    int lane = threadIdx.x & 63;
    int n = blockIdx.x * 4 + wave;
    if (n >= NN) return;
    int s = row_ptr[n];
    int e = row_ptr[n + 1];
    float a0a = 0.f, a1a = 0.f, a0b = 0.f, a1b = 0.f;
    int i = s;
    for (; i + 1 < e; i += 2) {                    // 2-way unroll: MLP
        unsigned p0 = packed[i];
        unsigned p1 = packed[i + 1];
        unsigned hv0 = T32[(size_t)(p0 & 0xffffu) * TROW + (p0 >> 16) * 64 + lane];
        unsigned hv1 = T32[(size_t)(p1 & 0xffffu) * TROW + (p1 >> 16) * 64 + lane];
        a0a += __uint_as_float(hv0 << 16);
        a1a += __uint_as_float(hv0 & 0xffff0000u);
        a0b += __uint_as_float(hv1 << 16);
        a1b += __uint_as_float(hv1 & 0xffff0000u);
    }
    if (i < e) {
        unsigned p0 = packed[i];
        unsigned hv0 = T32[(size_t)(p0 & 0xffffu) * TROW + (p0 >> 16) * 64 + lane];
        a0a += __uint_as_float(hv0 << 16);
        a1a += __uint_as_float(hv0 & 0xffff0000u);
    }
    float norm = node_norm[n];
    unsigned self = T32[(size_t)n * TROW + RR * 64 + lane];
    float x0 = (a0a + a0b) * norm + __uint_as_float(self << 16);
    float x1 = (a1a + a1b) * norm + __uint_as_float(self & 0xffff0000u);
    int d0 = lane * 2, d1 = lane * 2 + 1;
    float s0 = bn_gamma[d0] * rsqrtf(bn_var[d0] + BN_EPS);
    float s1 = bn_gamma[d1] * rsqrtf(bn_var[d1] + BN_EPS);
    x0 = fmaxf(x0 * s0 + bn_beta[d0] - bn_mean[d0] * s0, 0.f);
    x1 = fmaxf(x1 * s1 + bn_beta[d1] - bn_mean[d1] * s1, 0.f);
    if (out_fp32) {
        float2 o; o.x = x0; o.y = x1;
        *(float2*)&((float*)outp)[(size_t)n * Dh + lane * 2] = o;
    } else {
        ((unsigned*)outp)[(size_t)n * 64 + lane] =
            (unsigned)f2bf(x0) | ((unsigned)f2bf(x1) << 16);
    }
}

// ---------------------------------------------------------------------------
extern "C" void kernel_launch(void* const* d_in, const int* in_sizes, int n_in,
                              void* d_out, int out_size, void* d_ws, size_t ws_size,
                              hipStream_t stream)
{
    const float* node_feat = (const float*)d_in[0];
    const float* W_emb     = (const float*)d_in[1];
    const float* b_emb     = (const float*)d_in[2];
    const float* bases     = (const float*)d_in[3];
    const float* w_coe     = (const float*)d_in[4];
    const float* self_loop = (const float*)d_in[5];
    const float* bn_gamma  = (const float*)d_in[6];
    const float* bn_beta   = (const float*)d_in[7];
    const float* bn_mean   = (const float*)d_in[8];
    const float* bn_var    = (const float*)d_in[9];
    const int*   src       = (const int*)d_in[10];
    const int*   dst       = (const int*)d_in[11];
    const int*   etype     = (const int*)d_in[12];

    char* ws = (char*)d_ws;
    size_t off = 0;
    unsigned short* T = (unsigned short*)(ws + off);      off += (size_t)NN * NW * 2;        // 115.2 MB
    unsigned short* h1 = (unsigned short*)(ws + off);     off += (size_t)NN * Dh * 2;        // 12.8 MB
    unsigned short* nf_bf = (unsigned short*)(ws + off);  off += (size_t)NN * Dh * 2;        // 12.8 MB
    float* wideT = (float*)(ws + off);                    off += (size_t)LL * NW * Dh * 4;   // 1.18 MB
    float* wembT32 = (float*)(ws + off);                  off += (size_t)Dh * Dh * 4;
    unsigned short* WF0T = (unsigned short*)(ws + off);   off += (size_t)NW * Dh * 2;
    unsigned short* wcatT1 = (unsigned short*)(ws + off); off += (size_t)NW * Dh * 2;
    float* bf0 = (float*)(ws + off);                      off += (size_t)NW * 4;
    float* node_norm = (float*)(ws + off);                off += (size_t)NN * 4;
    int* counts = (int*)(ws + off);                       off += (size_t)NR * 4;             // 1.6 MB
    int* deg = (int*)(ws + off);                          off += (size_t)NN * 4;
    int* row_ptr = (int*)(ws + off);                      off += ((size_t)NN + 4) * 4;
    int* cursor = (int*)(ws + off);                       off += (size_t)NN * 4;
    int* bsum = (int*)(ws + off);                         off += 256 * 4;
    int* boffset = (int*)(ws + off);                      off += 257 * 4;
    unsigned* packed = (unsigned*)(ws + off);             off += (size_t)EE * 4;             // 3.2 MB

    const int edge_blocks = (EE + 255) / 256;        // 3125
    const int node_blocks = (NN + 255) / 256;        // 196
    const int n8 = NN * Dh / 8;                      // 800000
    dim3 gemm_grid((NN + 127) / 128, NW / 128);      // 391 x 9

    // weight prep: wide transforms, embed folding, input cast
    build_wideT_kernel<<<(LL * NW * Dh) / 256, 256, 0, stream>>>(bases, w_coe, self_loop,
                                                                 wideT, wcatT1);
    build_wembT_kernel<<<(Dh * Dh) / 256, 256, 0, stream>>>(W_emb, wembT32);
    fold_w_kernel<<<(NW * Dh) / 256, 256, 0, stream>>>(wideT, wembT32, WF0T);
    fold_b_kernel<<<(NW + 255) / 256, 256, 0, stream>>>(wideT, b_emb, bf0);
    convert_nf_kernel<<<(n8 + 255) / 256, 256, 0, stream>>>(node_feat, nf_bf, n8);

    // graph structure
    hipMemsetAsync(counts, 0, (size_t)NR * 4, stream);
    count_kernel<<<edge_blocks, 256, 0, stream>>>(dst, etype, counts);
    norm_deg_kernel<<<node_blocks, 256, 0, stream>>>(counts, node_norm, deg);
    scan1_kernel<<<node_blocks, 256, 0, stream>>>(deg, row_ptr, bsum);
    scan2_kernel<<<1, 256, 0, stream>>>(bsum, boffset);
    scan3_kernel<<<node_blocks, 256, 0, stream>>>(row_ptr, cursor, boffset);
    fill_kernel<<<edge_blocks, 256, 0, stream>>>(src, dst, etype, cursor, packed);

    // layer 0: T0 = nf @ (W_emb . Wwide0) + b_emb . Wwide0  (embed folded in)
    gemm_wide_kernel<<<gemm_grid, 256, 0, stream>>>(nf_bf, WF0T, bf0, T, NN);
    agg_fused_kernel<<<(NN + 3) / 4, 256, 0, stream>>>((const unsigned*)T, row_ptr, packed,
                                                       node_norm,
                                                       bn_gamma, bn_beta, bn_mean, bn_var,
                                                       h1, 0);
    // layer 1: T1 = h1 @ Wwide1, then fused agg -> d_out (fp32)
    gemm_wide_kernel<<<gemm_grid, 256, 0, stream>>>(h1, wcatT1, nullptr, T, NN);
    agg_fused_kernel<<<(NN + 3) / 4, 256, 0, stream>>>((const unsigned*)T, row_ptr, packed,
                                                       node_norm,
                                                       bn_gamma + Dh, bn_beta + Dh,
                                                       bn_mean + Dh, bn_var + Dh,
                                                       d_out, 1);
}